// Round 2
// baseline (686.181 us; speedup 1.0000x reference)
//
#include <hip/hip_runtime.h>
#include <cmath>

typedef __attribute__((ext_vector_type(8))) __bf16 v8bf;
typedef __attribute__((ext_vector_type(4))) float  v4f;

#define DEV static __device__ __forceinline__

DEV unsigned short f2bf(float f) {
  unsigned u = __builtin_bit_cast(unsigned, f);
  unsigned r = u + 0x7fffu + ((u >> 16) & 1u);   // RNE
  return (unsigned short)(r >> 16);
}
DEV float bf2f(unsigned short s) {
  return __builtin_bit_cast(float, ((unsigned)s) << 16);
}
DEV v8bf ld8(const unsigned short* p) { return *(const v8bf*)p; }

// ---------------- prep kernels ----------------
__global__ __launch_bounds__(256) void k_cvt_x(const float* __restrict__ x,
                                               unsigned short* __restrict__ xb) {
  int i = blockIdx.x * 256 + threadIdx.x;          // grid 4096 -> i < 1048576 (=4096*1024/4)
  float4 v = ((const float4*)x)[i];
  unsigned lo = (unsigned)f2bf(v.x) | ((unsigned)f2bf(v.y) << 16);
  unsigned hi = (unsigned)f2bf(v.z) | ((unsigned)f2bf(v.w) << 16);
  ((uint2*)xb)[i] = make_uint2(lo, hi);
}

// dst[n][k] = (bf16) src[k][n]   (src fp32 1024x1024 row-major)
__global__ __launch_bounds__(256) void k_trans_w(const float* __restrict__ src,
                                                 unsigned short* __restrict__ dst) {
  __shared__ float t[32][33];
  int n0 = blockIdx.x * 32, k0 = blockIdx.y * 32;
  int tx = threadIdx.x, ty = threadIdx.y;
  for (int r = ty; r < 32; r += 8)
    t[r][tx] = src[(k0 + r) * 1024 + n0 + tx];
  __syncthreads();
  for (int r = ty; r < 32; r += 8)
    dst[(n0 + r) * 1024 + k0 + tx] = f2bf(t[tx][r]);
}

__global__ __launch_bounds__(256) void k_bias(const float* __restrict__ bq,
                                              const float* __restrict__ bk,
                                              const float* __restrict__ bv,
                                              float* __restrict__ dst) {
  int i = blockIdx.x * 256 + threadIdx.x;          // grid 12 -> 3072
  float v = (i < 1024) ? bq[i] : (i < 2048 ? bk[i - 1024] : bv[i - 2048]);
  dst[i] = v;
}

// ---------------- bf16 MFMA GEMM: C[M][N] = A[M][K] * Bt[N][K]^T + bias ----------------
// M=4096 (grid.y*128), K=1024. 128x128 tile, BK=32, 4 waves each 64x64.
template <bool OUT_F32>
__global__ __launch_bounds__(256) void k_gemm(const unsigned short* __restrict__ A,
                                              const unsigned short* __restrict__ Bt,
                                              const float* __restrict__ bias,
                                              void* __restrict__ Cout,
                                              int ldc) {
  constexpr int K = 1024;
  __shared__ __attribute__((aligned(16))) unsigned short As[128 * 32];
  __shared__ __attribute__((aligned(16))) unsigned short Bs[128 * 32];
  int tid = threadIdx.x;
  int wave = tid >> 6, lane = tid & 63;
  int m0 = blockIdx.y * 128, n0 = blockIdx.x * 128;
  int wm = (wave >> 1) * 64, wn = (wave & 1) * 64;
  int m = lane & 15, q4 = lane >> 4;
  int arow = tid >> 2, acol = (tid & 3) * 8;       // each thread stages 16B x4
  v4f acc[4][4] = {};
  const unsigned short* pa0 = A + (m0 + arow) * K + acol;
  const unsigned short* pa1 = A + (m0 + 64 + arow) * K + acol;
  const unsigned short* pb0 = Bt + (n0 + arow) * K + acol;
  const unsigned short* pb1 = Bt + (n0 + 64 + arow) * K + acol;

  for (int kt = 0; kt < K; kt += 32) {
    v8bf a0 = ld8(pa0 + kt), a1 = ld8(pa1 + kt);
    v8bf b0 = ld8(pb0 + kt), b1 = ld8(pb1 + kt);
    __syncthreads();                                // prev iter's reads done
    *(v8bf*)&As[arow * 32 + acol] = a0;
    *(v8bf*)&As[(64 + arow) * 32 + acol] = a1;
    *(v8bf*)&Bs[arow * 32 + acol] = b0;
    *(v8bf*)&Bs[(64 + arow) * 32 + acol] = b1;
    __syncthreads();
    v8bf af[4], bfv[4];
#pragma unroll
    for (int mt = 0; mt < 4; mt++) af[mt] = ld8(&As[(wm + mt * 16 + m) * 32 + q4 * 8]);
#pragma unroll
    for (int nt = 0; nt < 4; nt++) bfv[nt] = ld8(&Bs[(wn + nt * 16 + m) * 32 + q4 * 8]);
#pragma unroll
    for (int mt = 0; mt < 4; mt++)
#pragma unroll
      for (int nt = 0; nt < 4; nt++)
        acc[mt][nt] = __builtin_amdgcn_mfma_f32_16x16x32_bf16(af[mt], bfv[nt], acc[mt][nt], 0, 0, 0);
  }
  // epilogue: C/D layout row=(lane>>4)*4+r, col=lane&15
#pragma unroll
  for (int mt = 0; mt < 4; mt++)
#pragma unroll
    for (int nt = 0; nt < 4; nt++) {
      int col = n0 + wn + nt * 16 + m;
      float bb = bias[col];
#pragma unroll
      for (int r = 0; r < 4; r++) {
        int row = m0 + wm + mt * 16 + q4 * 4 + r;
        float v = acc[mt][nt][r] + bb;
        if (OUT_F32) ((float*)Cout)[row * ldc + col] = v;
        else ((unsigned short*)Cout)[row * ldc + col] = f2bf(v);
      }
    }
}

// ---------------- sliding-window attention ----------------
// QKV bf16 [4096][3072] (q|k|v per row). One block = (b, h, 64 queries), 4 waves x 16 q.
// Writes Oatt bf16 [4096][1024] and dense weights fp32 [B][H][S][S] (zeros + band).
__global__ __launch_bounds__(256) void k_attn(const unsigned short* __restrict__ QKV,
                                              unsigned short* __restrict__ Oatt,
                                              float* __restrict__ Wout) {
  constexpr int VTS = 208;   // Vt row stride (elems)
  constexpr int PSS = 168;   // Ps row stride (elems)
  __shared__ __attribute__((aligned(16))) unsigned short Vt[64 * VTS];       // 26.6 KB
  __shared__ __attribute__((aligned(16))) unsigned short Ps[4][16 * PSS];    // 21.5 KB
  int b = blockIdx.z, h = blockIdx.y, i0 = blockIdx.x * 64;
  int tid = threadIdx.x, wave = tid >> 6, lane = tid & 63;
  int kbase = i0 - 128;
  const int ld = 3072;
  const unsigned short* Qg = QKV + b * 2048 * ld + h * 64;
  const unsigned short* Kg = Qg + 1024;
  const unsigned short* Vg = Qg + 2048;

  // stage V transposed: Vt[d][j] over 192 keys [kbase, kbase+192)
  for (int c = tid; c < 192 * 16; c += 256) {
    int j = c >> 4, d0 = (c & 15) * 4;
    int jg = kbase + j; jg = jg < 0 ? 0 : jg;      // clamp; mask kills j<0
    uint2 v = *(const uint2*)(Vg + jg * ld + d0);
    Vt[(d0 + 0) * VTS + j] = (unsigned short)(v.x & 0xffffu);
    Vt[(d0 + 1) * VTS + j] = (unsigned short)(v.x >> 16);
    Vt[(d0 + 2) * VTS + j] = (unsigned short)(v.y & 0xffffu);
    Vt[(d0 + 3) * VTS + j] = (unsigned short)(v.y >> 16);
  }
  // FIX: zero Vt columns [192,208) for all d — wave 3's PV c=4 chunk reads
  // Vt cols 192..207 (paired with zero-padded P cols 144..159). These were
  // uninitialized LDS: 0 x NaN-pattern = NaN, the round-1 failure.
  for (int c = tid; c < 64 * 16; c += 256) {
    int d = c >> 4, j = 192 + (c & 15);
    Vt[d * VTS + j] = 0;
  }
  // zero Ps pad cols [144,168) so padded PV chunks contribute 0
  for (int c = lane; c < 16 * 24; c += 64)
    Ps[wave][(c / 24) * PSS + 144 + (c % 24)] = 0;
  __syncthreads();

  int qb = i0 + wave * 16;
  int m = lane & 15, q4 = lane >> 4;

  // Q A-fragments straight from global: A[m=lane&15][k=q4*8+j]
  const unsigned short* qrow = Qg + (qb + m) * ld;
  v8bf qa0 = ld8(qrow + q4 * 8);
  v8bf qa1 = ld8(qrow + 32 + q4 * 8);

  // scores: 9 key tiles of 16 covering keys [qb-128, qb+16)
  v4f sc[9];
#pragma unroll
  for (int n = 0; n < 9; n++) {
    int key = kbase + wave * 16 + n * 16 + m;
    int kg = key < 0 ? 0 : key;
    const unsigned short* krow = Kg + kg * ld;     // B[k][n=key]: lane n = lane&15
    v8bf kb0 = ld8(krow + q4 * 8);
    v8bf kb1 = ld8(krow + 32 + q4 * 8);
    v4f z = {0.f, 0.f, 0.f, 0.f};
    z = __builtin_amdgcn_mfma_f32_16x16x32_bf16(qa0, kb0, z, 0, 0, 0);
    z = __builtin_amdgcn_mfma_f32_16x16x32_bf16(qa1, kb1, z, 0, 0, 0);
    sc[n] = z;
  }
  // mask + scale; row-wise softmax. C layout: row=q4*4+r (query), col=m (key)
  float mx[4] = {-3e38f, -3e38f, -3e38f, -3e38f};
#pragma unroll
  for (int n = 0; n < 9; n++)
#pragma unroll
    for (int r = 0; r < 4; r++) {
      int i = qb + q4 * 4 + r;
      int j = kbase + wave * 16 + n * 16 + m;
      float v = sc[n][r] * 0.125f;                 // 1/sqrt(64)
      bool ok = (j >= 0) && (j <= i) && (j > i - 128);
      v = ok ? v : -3e38f;
      sc[n][r] = v;
      mx[r] = fmaxf(mx[r], v);
    }
#pragma unroll
  for (int o = 1; o < 16; o <<= 1)
#pragma unroll
    for (int r = 0; r < 4; r++) mx[r] = fmaxf(mx[r], __shfl_xor(mx[r], o, 64));
  float sum[4] = {0.f, 0.f, 0.f, 0.f};
#pragma unroll
  for (int n = 0; n < 9; n++)
#pragma unroll
    for (int r = 0; r < 4; r++) {
      float p = __expf(sc[n][r] - mx[r]);          // masked -> 0
      sc[n][r] = p;
      sum[r] += p;
    }
#pragma unroll
  for (int o = 1; o < 16; o <<= 1)
#pragma unroll
    for (int r = 0; r < 4; r++) sum[r] += __shfl_xor(sum[r], o, 64);
  float inv[4];
#pragma unroll
  for (int r = 0; r < 4; r++) inv[r] = 1.0f / sum[r];

  // P -> LDS (A-operand layout source for PV)
#pragma unroll
  for (int n = 0; n < 9; n++)
#pragma unroll
    for (int r = 0; r < 4; r++)
      Ps[wave][(q4 * 4 + r) * PSS + n * 16 + m] = f2bf(sc[n][r] * inv[r]);
  __syncthreads();   // Ps write -> read edge (same wave, but keep it simple)

  // PV: out[16 q][64 d], 5 key-chunks of 32 (keys 144..159 are zero-padded P)
  v4f oacc[4] = {};
#pragma unroll
  for (int c = 0; c < 5; c++) {
    v8bf pa = ld8(&Ps[wave][m * PSS + c * 32 + q4 * 8]);
#pragma unroll
    for (int dt = 0; dt < 4; dt++) {
      v8bf vb = ld8(&Vt[(dt * 16 + m) * VTS + wave * 16 + c * 32 + q4 * 8]);
      oacc[dt] = __builtin_amdgcn_mfma_f32_16x16x32_bf16(pa, vb, oacc[dt], 0, 0, 0);
    }
  }
#pragma unroll
  for (int dt = 0; dt < 4; dt++)
#pragma unroll
    for (int r = 0; r < 4; r++)
      Oatt[(b * 2048 + qb + q4 * 4 + r) * 1024 + h * 64 + dt * 16 + m] = f2bf(oacc[dt][r]);

  // dense attention-weights rows: zeros + band, fully coalesced float4 stores
  float* wbase = Wout + (size_t)((b * 16 + h) * 2048) * 2048;
  for (int R = 0; R < 16; R++) {
    int i = qb + R;
    float* rowp = wbase + (size_t)i * 2048;
    int lo = i - 127;
    const unsigned short* prow = &Ps[wave][R * PSS];
    for (int it = 0; it < 8; it++) {
      int col = it * 256 + lane * 4;
      float4 v = {0.f, 0.f, 0.f, 0.f};
      if (col <= i && col + 3 >= lo) {
#pragma unroll
        for (int e = 0; e < 4; e++) {
          int j = col + e;
          if (j >= lo && j <= i && j >= 0)
            (&v.x)[e] = bf2f(prow[j - (qb - 128)]);
        }
      }
      *(float4*)(rowp + col) = v;
    }
  }
}

// ---------------- host launch ----------------
extern "C" void kernel_launch(void* const* d_in, const int* in_sizes, int n_in,
                              void* d_out, int out_size, void* d_ws, size_t ws_size,
                              hipStream_t stream) {
  (void)in_sizes; (void)n_in; (void)out_size; (void)ws_size;
  const float* x  = (const float*)d_in[0];
  const float* Wq = (const float*)d_in[1];
  const float* bq = (const float*)d_in[2];
  const float* Wk = (const float*)d_in[3];
  const float* bk = (const float*)d_in[4];
  const float* Wv = (const float*)d_in[5];
  const float* bv = (const float*)d_in[6];
  const float* Wo = (const float*)d_in[7];
  const float* bo = (const float*)d_in[8];

  char* ws = (char*)d_ws;
  unsigned short* xb   = (unsigned short*)(ws);                  //  8,388,608 B
  unsigned short* WT   = (unsigned short*)(ws + 8388608);        //  6,291,456 B  [3072][1024]
  unsigned short* WoT  = (unsigned short*)(ws + 14680064);       //  2,097,152 B  [1024][1024]
  float*          bqkv = (float*)(ws + 16777216);                //     12,288 B
  unsigned short* QKV  = (unsigned short*)(ws + 16789504);       // 25,165,824 B  [4096][3072]
  unsigned short* Oat  = (unsigned short*)(ws + 41955328);       //  8,388,608 B  [4096][1024]

  float* out  = (float*)d_out;          // [2,2048,1024]
  float* wout = out + 4194304;          // [2,16,2048,2048]

  k_cvt_x<<<4096, 256, 0, stream>>>(x, xb);
  k_trans_w<<<dim3(32, 32), dim3(32, 8), 0, stream>>>(Wq, WT);
  k_trans_w<<<dim3(32, 32), dim3(32, 8), 0, stream>>>(Wk, WT + 1024 * 1024);
  k_trans_w<<<dim3(32, 32), dim3(32, 8), 0, stream>>>(Wv, WT + 2 * 1024 * 1024);
  k_trans_w<<<dim3(32, 32), dim3(32, 8), 0, stream>>>(Wo, WoT);
  k_bias<<<12, 256, 0, stream>>>(bq, bk, bv, bqkv);
  k_gemm<false><<<dim3(24, 32), 256, 0, stream>>>(xb, WT, bqkv, QKV, 3072);
  k_attn<<<dim3(32, 16, 2), 256, 0, stream>>>(QKV, Oat, wout);
  k_gemm<true><<<dim3(8, 32), 256, 0, stream>>>(Oat, WoT, bo, out, 1024);
}